// Round 1
// baseline (1347.906 us; speedup 1.0000x reference)
//
#include <hip/hip_runtime.h>

typedef unsigned short u16;
typedef __attribute__((ext_vector_type(8))) __bf16 bf16x8;
typedef __attribute__((ext_vector_type(4))) float f32x4;

__device__ __forceinline__ u16 f2bf(float f) {
  union { float f; unsigned u; } v; v.f = f;
  unsigned r = v.u + 0x7fffu + ((v.u >> 16) & 1u);
  return (u16)(r >> 16);
}

__device__ __forceinline__ void gld16(const void* g, const void* l) {
  __builtin_amdgcn_global_load_lds((const __attribute__((address_space(1))) void*)g,
                                   (__attribute__((address_space(3))) void*)l, 16, 0, 0);
}

// ---------------- prep kernels ----------------

__global__ __launch_bounds__(256) void k_prep_params(
    const float* g1, const float* b1, const float* m1, const float* v1,
    const float* g2, const float* b2, const float* m2, const float* v2,
    const float* rw, float* scale1, float* shift1, float* scale2, float* shift2,
    float* cbf)
{
  int i = blockIdx.x * 256 + threadIdx.x;
  if (i < 64) {
    float s = g1[i] * rsqrtf(v1[i] + 1e-5f);
    scale1[i] = s; shift1[i] = b1[i] - m1[i] * s;
  } else if (i < 1088) {
    int c = i - 64;
    float s = g2[c] * rsqrtf(v2[c] + 1e-5f);
    scale2[c] = s; shift2[c] = b2[c] - m2[c] * s;
  } else if (i < 1728) {
    int n = i - 1088;
    cbf[n] = (n < 600) ? rw[n * 1025 + 1024] : 0.f;
  }
}

__global__ __launch_bounds__(256) void k_cast_w1(const float* w1, u16* w1b) {
  int i = blockIdx.x * 256 + threadIdx.x;  // 32768 total
  w1b[i] = f2bf(w1[i]);
}

__global__ __launch_bounds__(256) void k_cast_cwt(const float* rw, u16* cwt) {
  int i = blockIdx.x * 256 + threadIdx.x;  // 655360 total
  int n = i >> 10, c = i & 1023;
  cwt[i] = (n < 600) ? f2bf(rw[n * 1025 + c]) : (u16)0;
}

// w2 (1024,1280,3,3) OIHW -> w2t[t][o][ci] bf16 (K-contiguous rows)
__global__ __launch_bounds__(256) void k_prep_w2(const float* w2, u16* w2t) {
  __shared__ float buf[11520];
  int o = blockIdx.x;
  const float* src = w2 + (size_t)o * 11520;
  for (int i = threadIdx.x; i < 11520; i += 256) buf[i] = src[i];
  __syncthreads();
  for (int t = 0; t < 9; ++t) {
    u16* dst = w2t + ((size_t)t * 1024 + o) * 1280;
    for (int ci = threadIdx.x; ci < 1280; ci += 256) dst[ci] = f2bf(buf[ci * 9 + t]);
  }
}

// feat0 NCHW (64,1024,19,19) -> cat[b][1+h][1+w][256+c] bf16 (NHWC, padded 21x21)
__global__ __launch_bounds__(256) void k_feat0(const float* feat0, u16* cat) {
  __shared__ float tile[32][33];
  int b = blockIdx.z, c0 = blockIdx.y * 32, p0 = blockIdx.x * 32;
  int tid = threadIdx.x;
  int lo = tid & 31, hi = tid >> 5;  // hi 0..7
#pragma unroll
  for (int pass = 0; pass < 4; ++pass) {
    int cl = pass * 8 + hi;
    int p = p0 + lo;
    tile[cl][lo] = (p < 361) ? feat0[((size_t)(b * 1024 + c0 + cl)) * 361 + p] : 0.f;
  }
  __syncthreads();
#pragma unroll
  for (int pass = 0; pass < 4; ++pass) {
    int pl = pass * 8 + hi;
    int p = p0 + pl;
    if (p < 361) {
      int h = p / 19, w = p - h * 19;
      cat[(((size_t)b * 21 + 1 + h) * 21 + 1 + w) * 1280 + 256 + c0 + lo] = f2bf(tile[lo][pl]);
    }
  }
}

// ---------------- conv1 (1x1, 512->64) + BN + leaky + reorg -> cat ch 0..255 ----------------
// GEMM: M=92416 (= 64*1444 px), N=64, K=512.  BM=128 BN=64 BK=32, 4 waves (2x2), wave tile 64x32.
__global__ __launch_bounds__(256) void k_conv1(const float* feat1, const u16* w1b,
    const float* scale1, const float* shift1, u16* cat)
{
  __shared__ u16 As[128 * 40];  // stride 40 pad, element-staged
  __shared__ u16 Bs[64 * 32];
  int tid = threadIdx.x;
  int wave = tid >> 6, lane = tid & 63;
  int wr = wave >> 1, wc = wave & 1;
  int lm = lane & 15, lq = lane >> 4;
  int m0 = blockIdx.x * 128;

  int mLoc = tid & 127, cHalf = tid >> 7;
  int mA = m0 + mLoc;
  int bA = mA / 1444, qA = mA - bA * 1444;
  const float* aG = feat1 + ((size_t)bA * 512) * 1444 + qA;

  const u16* bG = w1b + (tid >> 2) * 512 + (tid & 3) * 8;
  char* BsW = (char*)Bs + wave * 1024;

  f32x4 acc[4][2];
#pragma unroll
  for (int i = 0; i < 4; ++i)
#pragma unroll
    for (int j = 0; j < 2; ++j)
#pragma unroll
      for (int r = 0; r < 4; ++r) acc[i][j][r] = 0.f;

  for (int k0 = 0; k0 < 512; k0 += 32) {
    gld16(bG + k0, BsW);
#pragma unroll
    for (int pass = 0; pass < 16; ++pass) {
      int c = pass * 2 + cHalf;
      As[mLoc * 40 + c] = f2bf(aG[(size_t)(k0 + c) * 1444]);
    }
    __syncthreads();
    bf16x8 aF[4], bF[2];
#pragma unroll
    for (int i = 0; i < 4; ++i)
      aF[i] = *(const bf16x8*)(As + (wr * 64 + i * 16 + lm) * 40 + lq * 8);
#pragma unroll
    for (int j = 0; j < 2; ++j)
      bF[j] = *(const bf16x8*)(Bs + (wc * 32 + j * 16 + lm) * 32 + lq * 8);
#pragma unroll
    for (int i = 0; i < 4; ++i)
#pragma unroll
      for (int j = 0; j < 2; ++j)
        acc[i][j] = __builtin_amdgcn_mfma_f32_16x16x32_bf16(aF[i], bF[j], acc[i][j], 0, 0, 0);
    __syncthreads();
  }

  int o0 = wc * 32;
  float sc[2], sh[2];
#pragma unroll
  for (int j = 0; j < 2; ++j) {
    int o = o0 + j * 16 + lm;
    sc[j] = scale1[o]; sh[j] = shift1[o];
  }
#pragma unroll
  for (int i = 0; i < 4; ++i) {
#pragma unroll
    for (int r = 0; r < 4; ++r) {
      int m = m0 + wr * 64 + i * 16 + lq * 4 + r;
      int b = m / 1444, q = m - b * 1444;
      int yy = q / 38, xx = q - yy * 38;
      size_t base = (((size_t)b * 21 + 1 + (yy >> 1)) * 21 + 1 + (xx >> 1)) * 1280
                  + ((yy & 1) * 2 + (xx & 1)) * 64;
#pragma unroll
      for (int j = 0; j < 2; ++j) {
        float v = acc[i][j][r] * sc[j] + sh[j];
        v = v > 0.f ? v : 0.1f * v;
        cat[base + o0 + j * 16 + lm] = f2bf(v);
      }
    }
  }
}

// ---------------- conv2 (3x3, 1280->1024) + BN + leaky -> pre[m][1024] bf16 ----------------
// Implicit GEMM: M=23104, N=1024, K=9*1280.  BM=BN=128, BK=32, m97-style global_load_lds staging.
__global__ __launch_bounds__(256) void k_conv2(const u16* cat, const u16* w2t,
    const float* scale2, const float* shift2, u16* pre)
{
  __shared__ u16 As[4096];
  __shared__ u16 Bs[4096];
  int tid = threadIdx.x;
  int wave = tid >> 6, lane = tid & 63;
  int wr = wave >> 1, wc = wave & 1;
  int lm = lane & 15, lq = lane >> 4;
  int n0 = blockIdx.x * 128, m0 = blockIdx.y * 128;

  int r0 = tid >> 2, seg = tid & 3;
  int mA0 = m0 + r0;       if (mA0 > 23103) mA0 = 23103;
  int mA1 = m0 + r0 + 64;  if (mA1 > 23103) mA1 = 23103;
  int b0 = mA0 / 361, p0 = mA0 - b0 * 361, y0 = p0 / 19, x0 = p0 - y0 * 19;
  int b1 = mA1 / 361, p1 = mA1 - b1 * 361, y1 = p1 / 19, x1 = p1 - y1 * 19;
  const u16* aP0 = cat + ((size_t)(b0 * 21 + y0) * 21 + x0) * 1280 + seg * 8;
  const u16* aP1 = cat + ((size_t)(b1 * 21 + y1) * 21 + x1) * 1280 + seg * 8;
  const u16* bP0 = w2t + (size_t)(n0 + r0) * 1280 + seg * 8;
  const u16* bP1 = bP0 + (size_t)64 * 1280;

  char* AsW0 = (char*)As + wave * 1024; char* AsW1 = AsW0 + 4096;
  char* BsW0 = (char*)Bs + wave * 1024; char* BsW1 = BsW0 + 4096;

  f32x4 acc[4][4];
#pragma unroll
  for (int i = 0; i < 4; ++i)
#pragma unroll
    for (int j = 0; j < 4; ++j)
#pragma unroll
      for (int r = 0; r < 4; ++r) acc[i][j][r] = 0.f;

#pragma unroll
  for (int t = 0; t < 9; ++t) {
    const int tapOff = ((t / 3) * 21 + (t % 3)) * 1280;
    const u16* a0 = aP0 + tapOff;
    const u16* a1 = aP1 + tapOff;
    const u16* bb0 = bP0 + (size_t)t * 1310720;
    const u16* bb1 = bP1 + (size_t)t * 1310720;
    for (int k = 0; k < 40; ++k) {
      int co = k * 32;
      gld16(a0 + co, AsW0);
      gld16(a1 + co, AsW1);
      gld16(bb0 + co, BsW0);
      gld16(bb1 + co, BsW1);
      __syncthreads();
      bf16x8 aF[4], bF[4];
#pragma unroll
      for (int i = 0; i < 4; ++i)
        aF[i] = *(const bf16x8*)(As + (wr * 64 + i * 16 + lm) * 32 + lq * 8);
#pragma unroll
      for (int j = 0; j < 4; ++j)
        bF[j] = *(const bf16x8*)(Bs + (wc * 64 + j * 16 + lm) * 32 + lq * 8);
#pragma unroll
      for (int i = 0; i < 4; ++i)
#pragma unroll
        for (int j = 0; j < 4; ++j)
          acc[i][j] = __builtin_amdgcn_mfma_f32_16x16x32_bf16(aF[i], bF[j], acc[i][j], 0, 0, 0);
      __syncthreads();
    }
  }

  int nn[4]; float sc[4], sh[4];
#pragma unroll
  for (int j = 0; j < 4; ++j) {
    nn[j] = n0 + wc * 64 + j * 16 + lm;
    sc[j] = scale2[nn[j]]; sh[j] = shift2[nn[j]];
  }
#pragma unroll
  for (int i = 0; i < 4; ++i) {
#pragma unroll
    for (int r = 0; r < 4; ++r) {
      int m = m0 + wr * 64 + i * 16 + lq * 4 + r;
      if (m < 23104) {
        u16* row = pre + (size_t)m * 1024;
#pragma unroll
        for (int j = 0; j < 4; ++j) {
          float v = acc[i][j][r] * sc[j] + sh[j];
          v = v > 0.f ? v : 0.1f * v;
          row[nn[j]] = f2bf(v);
        }
      }
    }
  }
}

// ---------------- einsum: det = pre(23104x1024) x cwt^T(640x1024) + cb -> out fp32 ----------------
__global__ __launch_bounds__(256) void k_einsum(const u16* pre, const u16* cwt,
    const float* cbf, float* out)
{
  __shared__ u16 As[4096];
  __shared__ u16 Bs[4096];
  int tid = threadIdx.x;
  int wave = tid >> 6, lane = tid & 63;
  int wr = wave >> 1, wc = wave & 1;
  int lm = lane & 15, lq = lane >> 4;
  int n0 = blockIdx.x * 128, m0 = blockIdx.y * 128;

  int r0 = tid >> 2, seg = tid & 3;
  int mA0 = m0 + r0;       if (mA0 > 23103) mA0 = 23103;
  int mA1 = m0 + r0 + 64;  if (mA1 > 23103) mA1 = 23103;
  const u16* aP0 = pre + (size_t)mA0 * 1024 + seg * 8;
  const u16* aP1 = pre + (size_t)mA1 * 1024 + seg * 8;
  const u16* bP0 = cwt + (size_t)(n0 + r0) * 1024 + seg * 8;
  const u16* bP1 = bP0 + (size_t)64 * 1024;

  char* AsW0 = (char*)As + wave * 1024; char* AsW1 = AsW0 + 4096;
  char* BsW0 = (char*)Bs + wave * 1024; char* BsW1 = BsW0 + 4096;

  f32x4 acc[4][4];
#pragma unroll
  for (int i = 0; i < 4; ++i)
#pragma unroll
    for (int j = 0; j < 4; ++j)
#pragma unroll
      for (int r = 0; r < 4; ++r) acc[i][j][r] = 0.f;

  for (int k0 = 0; k0 < 1024; k0 += 32) {
    gld16(aP0 + k0, AsW0);
    gld16(aP1 + k0, AsW1);
    gld16(bP0 + k0, BsW0);
    gld16(bP1 + k0, BsW1);
    __syncthreads();
    bf16x8 aF[4], bF[4];
#pragma unroll
    for (int i = 0; i < 4; ++i)
      aF[i] = *(const bf16x8*)(As + (wr * 64 + i * 16 + lm) * 32 + lq * 8);
#pragma unroll
    for (int j = 0; j < 4; ++j)
      bF[j] = *(const bf16x8*)(Bs + (wc * 64 + j * 16 + lm) * 32 + lq * 8);
#pragma unroll
    for (int i = 0; i < 4; ++i)
#pragma unroll
      for (int j = 0; j < 4; ++j)
        acc[i][j] = __builtin_amdgcn_mfma_f32_16x16x32_bf16(aF[i], bF[j], acc[i][j], 0, 0, 0);
    __syncthreads();
  }

  int nn[4]; float bias[4];
#pragma unroll
  for (int j = 0; j < 4; ++j) {
    nn[j] = n0 + wc * 64 + j * 16 + lm;  // < 640
    bias[j] = cbf[nn[j]];
  }
#pragma unroll
  for (int i = 0; i < 4; ++i) {
#pragma unroll
    for (int r = 0; r < 4; ++r) {
      int m = m0 + wr * 64 + i * 16 + lq * 4 + r;
      if (m < 23104) {
        int b = m / 361, p = m - b * 361;
        float* orow = out + (size_t)b * 600 * 361 + p;
#pragma unroll
        for (int j = 0; j < 4; ++j) {
          if (nn[j] < 600) orow[(size_t)nn[j] * 361] = acc[i][j][r] + bias[j];
        }
      }
    }
  }
}

// ---------------- launch ----------------

extern "C" void kernel_launch(void* const* d_in, const int* in_sizes, int n_in,
                              void* d_out, int out_size, void* d_ws, size_t ws_size,
                              hipStream_t stream) {
  const float* feat0 = (const float*)d_in[0];
  const float* feat1 = (const float*)d_in[1];
  const float* w1 = (const float*)d_in[2];
  const float* g1 = (const float*)d_in[3];
  const float* b1 = (const float*)d_in[4];
  const float* m1 = (const float*)d_in[5];
  const float* v1 = (const float*)d_in[6];
  const float* w2 = (const float*)d_in[7];
  const float* g2 = (const float*)d_in[8];
  const float* b2 = (const float*)d_in[9];
  const float* m2 = (const float*)d_in[10];
  const float* v2 = (const float*)d_in[11];
  const float* rw = (const float*)d_in[12];
  float* out = (float*)d_out;

  char* ws = (char*)d_ws;
  u16* cat    = (u16*)(ws);                    // 64*21*21*1280 bf16 = 72,253,440 B
  u16* w2t    = (u16*)(ws + 72253440);         // 9*1024*1280 bf16  = 23,592,960 B
  u16* pre    = (u16*)(ws + 95846400);         // 23104*1024 bf16   = 47,316,992 B
  u16* w1b    = (u16*)(ws + 143163392);        // 64*512 bf16       =     65,536 B
  u16* cwt    = (u16*)(ws + 143228928);        // 640*1024 bf16     =  1,310,720 B
  float* scale1 = (float*)(ws + 144539648);
  float* shift1 = (float*)(ws + 144539904);
  float* scale2 = (float*)(ws + 144540160);
  float* shift2 = (float*)(ws + 144544256);
  float* cbf    = (float*)(ws + 144548352);    // 640 floats; total ws use ~144.6 MB

  hipMemsetAsync(cat, 0, 72253440, stream);  // zero spatial padding (and interior, overwritten)

  k_prep_params<<<7, 256, 0, stream>>>(g1, b1, m1, v1, g2, b2, m2, v2, rw,
                                       scale1, shift1, scale2, shift2, cbf);
  k_cast_w1<<<128, 256, 0, stream>>>(w1, w1b);
  k_cast_cwt<<<2560, 256, 0, stream>>>(rw, cwt);
  k_prep_w2<<<1024, 256, 0, stream>>>(w2, w2t);
  k_feat0<<<dim3(12, 32, 64), 256, 0, stream>>>(feat0, cat);
  k_conv1<<<722, 256, 0, stream>>>(feat1, w1b, scale1, shift1, cat);
  k_conv2<<<dim3(8, 181), 256, 0, stream>>>(cat, w2t, scale2, shift2, pre);
  k_einsum<<<dim3(5, 181), 256, 0, stream>>>(pre, cwt, cbf, out);
}

// Round 2
// 1218.734 us; speedup vs baseline: 1.1060x; 1.1060x over previous
//
#include <hip/hip_runtime.h>

typedef unsigned short u16;
typedef __attribute__((ext_vector_type(8))) __bf16 bf16x8;
typedef __attribute__((ext_vector_type(4))) float f32x4;

__device__ __forceinline__ u16 f2bf(float f) {
  union { float f; unsigned u; } v; v.f = f;
  unsigned r = v.u + 0x7fffu + ((v.u >> 16) & 1u);
  return (u16)(r >> 16);
}

__device__ __forceinline__ void gld16(const void* g, const void* l) {
  __builtin_amdgcn_global_load_lds((const __attribute__((address_space(1))) void*)g,
                                   (__attribute__((address_space(3))) void*)l, 16, 0, 0);
}

// ---------------- prep kernels ----------------

__global__ __launch_bounds__(256) void k_prep_params(
    const float* g1, const float* b1, const float* m1, const float* v1,
    const float* g2, const float* b2, const float* m2, const float* v2,
    const float* rw, float* scale1, float* shift1, float* scale2, float* shift2,
    float* cbf)
{
  int i = blockIdx.x * 256 + threadIdx.x;
  if (i < 64) {
    float s = g1[i] * rsqrtf(v1[i] + 1e-5f);
    scale1[i] = s; shift1[i] = b1[i] - m1[i] * s;
  } else if (i < 1088) {
    int c = i - 64;
    float s = g2[c] * rsqrtf(v2[c] + 1e-5f);
    scale2[c] = s; shift2[c] = b2[c] - m2[c] * s;
  } else if (i < 1728) {
    int n = i - 1088;
    cbf[n] = (n < 600) ? rw[n * 1025 + 1024] : 0.f;
  }
}

__global__ __launch_bounds__(256) void k_cast_w1(const float* w1, u16* w1b) {
  int i = blockIdx.x * 256 + threadIdx.x;  // 32768 total
  w1b[i] = f2bf(w1[i]);
}

__global__ __launch_bounds__(256) void k_cast_cwt(const float* rw, u16* cwt) {
  int i = blockIdx.x * 256 + threadIdx.x;  // 655360 total
  int n = i >> 10, c = i & 1023;
  cwt[i] = (n < 600) ? f2bf(rw[n * 1025 + c]) : (u16)0;
}

// w2 (1024,1280,3,3) OIHW -> w2t[dy][o][dx*1280+ci] bf16 (per-dy K=3840 contiguous rows)
__global__ __launch_bounds__(256) void k_prep_w2(const float* w2, u16* w2t) {
  __shared__ float buf[11520];
  int o = blockIdx.x;
  const float* src = w2 + (size_t)o * 11520;
  for (int i = threadIdx.x; i < 11520; i += 256) buf[i] = src[i];
  __syncthreads();
  for (int t = 0; t < 9; ++t) {
    int dy = t / 3, dx = t - dy * 3;
    u16* dst = w2t + ((size_t)dy * 1024 + o) * 3840 + dx * 1280;
    for (int ci = threadIdx.x; ci < 1280; ci += 256) dst[ci] = f2bf(buf[ci * 9 + t]);
  }
}

// feat0 NCHW (64,1024,19,19) -> cat[b][1+h][1+w][256+c] bf16 (NHWC, padded 21x21)
__global__ __launch_bounds__(256) void k_feat0(const float* feat0, u16* cat) {
  __shared__ float tile[32][33];
  int b = blockIdx.z, c0 = blockIdx.y * 32, p0 = blockIdx.x * 32;
  int tid = threadIdx.x;
  int lo = tid & 31, hi = tid >> 5;  // hi 0..7
#pragma unroll
  for (int pass = 0; pass < 4; ++pass) {
    int cl = pass * 8 + hi;
    int p = p0 + lo;
    tile[cl][lo] = (p < 361) ? feat0[((size_t)(b * 1024 + c0 + cl)) * 361 + p] : 0.f;
  }
  __syncthreads();
#pragma unroll
  for (int pass = 0; pass < 4; ++pass) {
    int pl = pass * 8 + hi;
    int p = p0 + pl;
    if (p < 361) {
      int h = p / 19, w = p - h * 19;
      cat[(((size_t)b * 21 + 1 + h) * 21 + 1 + w) * 1280 + 256 + c0 + lo] = f2bf(tile[lo][pl]);
    }
  }
}

// ---------------- conv1 (1x1, 512->64) + BN + leaky + reorg -> cat ch 0..255 ----------------
__global__ __launch_bounds__(256) void k_conv1(const float* feat1, const u16* w1b,
    const float* scale1, const float* shift1, u16* cat)
{
  __shared__ u16 As[128 * 40];
  __shared__ u16 Bs[64 * 32];
  int tid = threadIdx.x;
  int wave = tid >> 6, lane = tid & 63;
  int wr = wave >> 1, wc = wave & 1;
  int lm = lane & 15, lq = lane >> 4;
  int m0 = blockIdx.x * 128;

  int mLoc = tid & 127, cHalf = tid >> 7;
  int mA = m0 + mLoc;
  int bA = mA / 1444, qA = mA - bA * 1444;
  const float* aG = feat1 + ((size_t)bA * 512) * 1444 + qA;

  const u16* bG = w1b + (tid >> 2) * 512 + (tid & 3) * 8;
  char* BsW = (char*)Bs + wave * 1024;

  f32x4 acc[4][2];
#pragma unroll
  for (int i = 0; i < 4; ++i)
#pragma unroll
    for (int j = 0; j < 2; ++j)
#pragma unroll
      for (int r = 0; r < 4; ++r) acc[i][j][r] = 0.f;

  for (int k0 = 0; k0 < 512; k0 += 32) {
    gld16(bG + k0, BsW);
#pragma unroll
    for (int pass = 0; pass < 16; ++pass) {
      int c = pass * 2 + cHalf;
      As[mLoc * 40 + c] = f2bf(aG[(size_t)(k0 + c) * 1444]);
    }
    __syncthreads();
    bf16x8 aF[4], bF[2];
#pragma unroll
    for (int i = 0; i < 4; ++i)
      aF[i] = *(const bf16x8*)(As + (wr * 64 + i * 16 + lm) * 40 + lq * 8);
#pragma unroll
    for (int j = 0; j < 2; ++j)
      bF[j] = *(const bf16x8*)(Bs + (wc * 32 + j * 16 + lm) * 32 + lq * 8);
#pragma unroll
    for (int i = 0; i < 4; ++i)
#pragma unroll
      for (int j = 0; j < 2; ++j)
        acc[i][j] = __builtin_amdgcn_mfma_f32_16x16x32_bf16(aF[i], bF[j], acc[i][j], 0, 0, 0);
    __syncthreads();
  }

  int o0 = wc * 32;
  float sc[2], sh[2];
#pragma unroll
  for (int j = 0; j < 2; ++j) {
    int o = o0 + j * 16 + lm;
    sc[j] = scale1[o]; sh[j] = shift1[o];
  }
#pragma unroll
  for (int i = 0; i < 4; ++i) {
#pragma unroll
    for (int r = 0; r < 4; ++r) {
      int m = m0 + wr * 64 + i * 16 + lq * 4 + r;
      int b = m / 1444, q = m - b * 1444;
      int yy = q / 38, xx = q - yy * 38;
      size_t base = (((size_t)b * 21 + 1 + (yy >> 1)) * 21 + 1 + (xx >> 1)) * 1280
                  + ((yy & 1) * 2 + (xx & 1)) * 64;
#pragma unroll
      for (int j = 0; j < 2; ++j) {
        float v = acc[i][j][r] * sc[j] + sh[j];
        v = v > 0.f ? v : 0.1f * v;
        cat[base + o0 + j * 16 + lm] = f2bf(v);
      }
    }
  }
}

// ---------------- conv2 (3x3, 1280->1024) + BN + leaky -> pre[m][1024] bf16 ----------------
// Implicit GEMM, BK=64 as two 32-K panels. M=23104, N=1024, K=3*3840.
// LDS per operand: [2 panels][128 rows][32 u16] = 16 KB; A+B = 32 KB.
__global__ __launch_bounds__(256) void k_conv2(const u16* cat, const u16* w2t,
    const float* scale2, const float* shift2, u16* pre)
{
  __shared__ u16 As[8192];
  __shared__ u16 Bs[8192];
  int tid = threadIdx.x;
  int wave = tid >> 6, lane = tid & 63;
  int wr = wave >> 1, wc = wave & 1;
  int lm = lane & 15, lq = lane >> 4;
  int n0 = blockIdx.x * 128, m0 = blockIdx.y * 128;

  int rIn = lane >> 2;            // 0..15
  int kseg = (lane & 3) * 8;      // u16 offset within 32-K panel
  int rowLo = wave * 16 + rIn;    // 0..63

  // A rows (pixels), clamped
  int mLo = m0 + rowLo;       if (mLo > 23103) mLo = 23103;
  int mHi = m0 + rowLo + 64;  if (mHi > 23103) mHi = 23103;
  int bL = mLo / 361, pL = mLo - bL * 361, yL = pL / 19, xL = pL - yL * 19;
  int bH = mHi / 361, pH = mHi - bH * 361, yH = pH / 19, xH = pH - yH * 19;
  const u16* aLo = cat + ((size_t)(bL * 21 + yL) * 21 + xL) * 1280 + kseg;
  const u16* aHi = cat + ((size_t)(bH * 21 + yH) * 21 + xH) * 1280 + kseg;
  // B rows (out channels)
  const u16* bLo = w2t + (size_t)(n0 + rowLo) * 3840 + kseg;
  const u16* bHi = bLo + (size_t)64 * 3840;

  // LDS staging bases (u16 units; each issue covers 1 KB = 16 rows x 64 B)
  u16* asJ0 = As + wave * 512;          u16* asJ1 = As + (4 + wave) * 512;
  u16* asJ2 = As + 4096 + wave * 512;   u16* asJ3 = As + 4096 + (4 + wave) * 512;
  u16* bsJ0 = Bs + wave * 512;          u16* bsJ1 = Bs + (4 + wave) * 512;
  u16* bsJ2 = Bs + 4096 + wave * 512;   u16* bsJ3 = Bs + 4096 + (4 + wave) * 512;

  f32x4 acc[4][4];
#pragma unroll
  for (int i = 0; i < 4; ++i)
#pragma unroll
    for (int j = 0; j < 4; ++j)
#pragma unroll
      for (int r = 0; r < 4; ++r) acc[i][j][r] = 0.f;

  for (int dy = 0; dy < 3; ++dy) {
    const u16* a0 = aLo + dy * 26880;             // 21*1280
    const u16* a1 = aHi + dy * 26880;
    const u16* b0 = bLo + (size_t)dy * 3932160;   // 1024*3840
    const u16* b1 = bHi + (size_t)dy * 3932160;
    for (int k0 = 0; k0 < 3840; k0 += 64) {
      gld16(a0 + k0,      asJ0);
      gld16(a1 + k0,      asJ1);
      gld16(a0 + k0 + 32, asJ2);
      gld16(a1 + k0 + 32, asJ3);
      gld16(b0 + k0,      bsJ0);
      gld16(b1 + k0,      bsJ1);
      gld16(b0 + k0 + 32, bsJ2);
      gld16(b1 + k0 + 32, bsJ3);
      __syncthreads();
#pragma unroll
      for (int kk = 0; kk < 2; ++kk) {
        bf16x8 aF[4], bF[4];
#pragma unroll
        for (int i = 0; i < 4; ++i)
          aF[i] = *(const bf16x8*)(As + kk * 4096 + (wr * 64 + i * 16 + lm) * 32 + lq * 8);
#pragma unroll
        for (int j = 0; j < 4; ++j)
          bF[j] = *(const bf16x8*)(Bs + kk * 4096 + (wc * 64 + j * 16 + lm) * 32 + lq * 8);
#pragma unroll
        for (int i = 0; i < 4; ++i)
#pragma unroll
          for (int j = 0; j < 4; ++j)
            acc[i][j] = __builtin_amdgcn_mfma_f32_16x16x32_bf16(aF[i], bF[j], acc[i][j], 0, 0, 0);
      }
      __syncthreads();
    }
  }

  int nn[4]; float sc[4], sh[4];
#pragma unroll
  for (int j = 0; j < 4; ++j) {
    nn[j] = n0 + wc * 64 + j * 16 + lm;
    sc[j] = scale2[nn[j]]; sh[j] = shift2[nn[j]];
  }
#pragma unroll
  for (int i = 0; i < 4; ++i) {
#pragma unroll
    for (int r = 0; r < 4; ++r) {
      int m = m0 + wr * 64 + i * 16 + lq * 4 + r;
      if (m < 23104) {
        u16* row = pre + (size_t)m * 1024;
#pragma unroll
        for (int j = 0; j < 4; ++j) {
          float v = acc[i][j][r] * sc[j] + sh[j];
          v = v > 0.f ? v : 0.1f * v;
          row[nn[j]] = f2bf(v);
        }
      }
    }
  }
}

// ---------------- einsum: det[cw=600 rows][pix=23104] ; A=cwt(640x1024), B=pre(23104x1024) ----
// C col = pixel (coalesced stores), C row = cw index.
__global__ __launch_bounds__(256) void k_einsum(const u16* pre, const u16* cwt,
    const float* cbf, float* out)
{
  __shared__ u16 As[4096];
  __shared__ u16 Bs[4096];
  int tid = threadIdx.x;
  int wave = tid >> 6, lane = tid & 63;
  int wr = wave >> 1, wc = wave & 1;
  int lm = lane & 15, lq = lane >> 4;
  int n0 = blockIdx.x * 128;   // pixel block
  int m0 = blockIdx.y * 128;   // cw-row block (0..512)

  int r0 = tid >> 2, seg = (tid & 3) * 8;
  const u16* aP0 = cwt + (size_t)(m0 + r0) * 1024 + seg;        // rows < 640
  const u16* aP1 = aP0 + (size_t)64 * 1024;
  int q0 = n0 + r0;       if (q0 > 23103) q0 = 23103;
  int q1 = n0 + r0 + 64;  if (q1 > 23103) q1 = 23103;
  const u16* bP0 = pre + (size_t)q0 * 1024 + seg;
  const u16* bP1 = pre + (size_t)q1 * 1024 + seg;

  char* AsW = (char*)As + wave * 1024;
  char* BsW = (char*)Bs + wave * 1024;

  f32x4 acc[4][4];
#pragma unroll
  for (int i = 0; i < 4; ++i)
#pragma unroll
    for (int j = 0; j < 4; ++j)
#pragma unroll
      for (int r = 0; r < 4; ++r) acc[i][j][r] = 0.f;

  for (int k0 = 0; k0 < 1024; k0 += 32) {
    gld16(aP0 + k0, AsW);
    gld16(aP1 + k0, AsW + 4096);
    gld16(bP0 + k0, BsW);
    gld16(bP1 + k0, BsW + 4096);
    __syncthreads();
    bf16x8 aF[4], bF[4];
#pragma unroll
    for (int i = 0; i < 4; ++i)
      aF[i] = *(const bf16x8*)(As + (wr * 64 + i * 16 + lm) * 32 + lq * 8);
#pragma unroll
    for (int j = 0; j < 4; ++j)
      bF[j] = *(const bf16x8*)(Bs + (wc * 64 + j * 16 + lm) * 32 + lq * 8);
#pragma unroll
    for (int i = 0; i < 4; ++i)
#pragma unroll
      for (int j = 0; j < 4; ++j)
        acc[i][j] = __builtin_amdgcn_mfma_f32_16x16x32_bf16(aF[i], bF[j], acc[i][j], 0, 0, 0);
    __syncthreads();
  }

  // epilogue: row = cw index, col = pixel (coalesced along lm)
  int pix[4], pb[4], pp[4];
#pragma unroll
  for (int j = 0; j < 4; ++j) {
    pix[j] = n0 + wc * 64 + j * 16 + lm;
    int b = pix[j] / 361;
    pb[j] = b; pp[j] = pix[j] - b * 361;
  }
#pragma unroll
  for (int i = 0; i < 4; ++i) {
#pragma unroll
    for (int r = 0; r < 4; ++r) {
      int cw = m0 + wr * 64 + i * 16 + lq * 4 + r;
      if (cw < 600) {
        float bias = cbf[cw];
#pragma unroll
        for (int j = 0; j < 4; ++j) {
          if (pix[j] < 23104)
            out[(size_t)pb[j] * 216600 + (size_t)cw * 361 + pp[j]] = acc[i][j][r] + bias;
        }
      }
    }
  }
}

// ---------------- launch ----------------

extern "C" void kernel_launch(void* const* d_in, const int* in_sizes, int n_in,
                              void* d_out, int out_size, void* d_ws, size_t ws_size,
                              hipStream_t stream) {
  const float* feat0 = (const float*)d_in[0];
  const float* feat1 = (const float*)d_in[1];
  const float* w1 = (const float*)d_in[2];
  const float* g1 = (const float*)d_in[3];
  const float* b1 = (const float*)d_in[4];
  const float* m1 = (const float*)d_in[5];
  const float* v1 = (const float*)d_in[6];
  const float* w2 = (const float*)d_in[7];
  const float* g2 = (const float*)d_in[8];
  const float* b2 = (const float*)d_in[9];
  const float* m2 = (const float*)d_in[10];
  const float* v2 = (const float*)d_in[11];
  const float* rw = (const float*)d_in[12];
  float* out = (float*)d_out;

  char* ws = (char*)d_ws;
  u16* cat    = (u16*)(ws);                    // 64*21*21*1280 bf16 = 72,253,440 B
  u16* w2t    = (u16*)(ws + 72253440);         // 3*1024*3840 bf16  = 23,592,960 B
  u16* pre    = (u16*)(ws + 95846400);         // 23104*1024 bf16   = 47,316,992 B
  u16* w1b    = (u16*)(ws + 143163392);        // 64*512 bf16
  u16* cwt    = (u16*)(ws + 143228928);        // 640*1024 bf16
  float* scale1 = (float*)(ws + 144539648);
  float* shift1 = (float*)(ws + 144539904);
  float* scale2 = (float*)(ws + 144540160);
  float* shift2 = (float*)(ws + 144544256);
  float* cbf    = (float*)(ws + 144548352);

  hipMemsetAsync(cat, 0, 72253440, stream);  // zero spatial padding

  k_prep_params<<<7, 256, 0, stream>>>(g1, b1, m1, v1, g2, b2, m2, v2, rw,
                                       scale1, shift1, scale2, shift2, cbf);
  k_cast_w1<<<128, 256, 0, stream>>>(w1, w1b);
  k_cast_cwt<<<2560, 256, 0, stream>>>(rw, cwt);
  k_prep_w2<<<1024, 256, 0, stream>>>(w2, w2t);
  k_feat0<<<dim3(12, 32, 64), 256, 0, stream>>>(feat0, cat);
  k_conv1<<<722, 256, 0, stream>>>(feat1, w1b, scale1, shift1, cat);
  k_conv2<<<dim3(8, 181), 256, 0, stream>>>(cat, w2t, scale2, shift2, pre);
  k_einsum<<<dim3(181, 5), 256, 0, stream>>>(pre, cwt, cbf, out);
}

// Round 3
// 1215.514 us; speedup vs baseline: 1.1089x; 1.0026x over previous
//
#include <hip/hip_runtime.h>

typedef unsigned short u16;
typedef __attribute__((ext_vector_type(8))) __bf16 bf16x8;
typedef __attribute__((ext_vector_type(4))) float f32x4;

__device__ __forceinline__ u16 f2bf(float f) {
  union { float f; unsigned u; } v; v.f = f;
  unsigned r = v.u + 0x7fffu + ((v.u >> 16) & 1u);
  return (u16)(r >> 16);
}

__device__ __forceinline__ void gld16(const void* g, const void* l) {
  __builtin_amdgcn_global_load_lds((const __attribute__((address_space(1))) void*)g,
                                   (__attribute__((address_space(3))) void*)l, 16, 0, 0);
}

// ---------------- merged small prep ----------------
// [0,32768): w1 cast; [32768, 32768+655360): cwt cast; then params.
__global__ __launch_bounds__(256) void k_prep_small(
    const float* w1, const float* rw,
    const float* g1, const float* b1, const float* m1, const float* v1,
    const float* g2, const float* b2, const float* m2, const float* v2,
    u16* w1b, u16* cwt,
    float* scale1, float* shift1, float* scale2, float* shift2, float* cbf)
{
  int i = blockIdx.x * 256 + threadIdx.x;
  if (i < 32768) { w1b[i] = f2bf(w1[i]); return; }
  i -= 32768;
  if (i < 655360) {
    int n = i >> 10, c = i & 1023;
    cwt[i] = (n < 600) ? f2bf(rw[n * 1025 + c]) : (u16)0;
    return;
  }
  i -= 655360;
  if (i < 64) {
    float s = g1[i] * rsqrtf(v1[i] + 1e-5f);
    scale1[i] = s; shift1[i] = b1[i] - m1[i] * s;
  } else if (i < 1088) {
    int c = i - 64;
    float s = g2[c] * rsqrtf(v2[c] + 1e-5f);
    scale2[c] = s; shift2[c] = b2[c] - m2[c] * s;
  } else if (i < 1728) {
    int n = i - 1088;
    cbf[n] = (n < 600) ? rw[n * 1025 + 1024] : 0.f;
  }
}

// w2 (1024,1280,3,3) OIHW -> w2t[dy][o][dx*1280+ci] bf16 (per-dy K=3840 contiguous rows)
__global__ __launch_bounds__(256) void k_prep_w2(const float* w2, u16* w2t) {
  __shared__ float buf[11520];
  int o = blockIdx.x;
  const float* src = w2 + (size_t)o * 11520;
  for (int i = threadIdx.x; i < 11520; i += 256) buf[i] = src[i];
  __syncthreads();
  for (int t = 0; t < 9; ++t) {
    int dy = t / 3, dx = t - dy * 3;
    u16* dst = w2t + ((size_t)dy * 1024 + o) * 3840 + dx * 1280;
    for (int ci = threadIdx.x; ci < 1280; ci += 256) dst[ci] = f2bf(buf[ci * 9 + t]);
  }
}

// feat0 NCHW (64,1024,19,19) -> cat[b][1+h][1+w][256+c] bf16 (NHWC, padded 21x21)
__global__ __launch_bounds__(256) void k_feat0(const float* feat0, u16* cat) {
  __shared__ float tile[32][33];
  int b = blockIdx.z, c0 = blockIdx.y * 32, p0 = blockIdx.x * 32;
  int tid = threadIdx.x;
  int lo = tid & 31, hi = tid >> 5;
#pragma unroll
  for (int pass = 0; pass < 4; ++pass) {
    int cl = pass * 8 + hi;
    int p = p0 + lo;
    tile[cl][lo] = (p < 361) ? feat0[((size_t)(b * 1024 + c0 + cl)) * 361 + p] : 0.f;
  }
  __syncthreads();
#pragma unroll
  for (int pass = 0; pass < 4; ++pass) {
    int pl = pass * 8 + hi;
    int p = p0 + pl;
    if (p < 361) {
      int h = p / 19, w = p - h * 19;
      cat[(((size_t)b * 21 + 1 + h) * 21 + 1 + w) * 1280 + 256 + c0 + lo] = f2bf(tile[lo][pl]);
    }
  }
}

// ---------------- conv1 (1x1, 512->64) + BN + leaky + reorg -> cat ch 0..255 ----------------
__global__ __launch_bounds__(256) void k_conv1(const float* feat1, const u16* w1b,
    const float* scale1, const float* shift1, u16* cat)
{
  __shared__ u16 As[128 * 40];
  __shared__ u16 Bs[64 * 32];
  int tid = threadIdx.x;
  int wave = tid >> 6, lane = tid & 63;
  int wr = wave >> 1, wc = wave & 1;
  int lm = lane & 15, lq = lane >> 4;
  int m0 = blockIdx.x * 128;

  int mLoc = tid & 127, cHalf = tid >> 7;
  int mA = m0 + mLoc;
  int bA = mA / 1444, qA = mA - bA * 1444;
  const float* aG = feat1 + ((size_t)bA * 512) * 1444 + qA;

  const u16* bG = w1b + (tid >> 2) * 512 + (tid & 3) * 8;
  char* BsW = (char*)Bs + wave * 1024;

  f32x4 acc[4][2];
#pragma unroll
  for (int i = 0; i < 4; ++i)
#pragma unroll
    for (int j = 0; j < 2; ++j)
#pragma unroll
      for (int r = 0; r < 4; ++r) acc[i][j][r] = 0.f;

  for (int k0 = 0; k0 < 512; k0 += 32) {
    gld16(bG + k0, BsW);
#pragma unroll
    for (int pass = 0; pass < 16; ++pass) {
      int c = pass * 2 + cHalf;
      As[mLoc * 40 + c] = f2bf(aG[(size_t)(k0 + c) * 1444]);
    }
    __syncthreads();
    bf16x8 aF[4], bF[2];
#pragma unroll
    for (int i = 0; i < 4; ++i)
      aF[i] = *(const bf16x8*)(As + (wr * 64 + i * 16 + lm) * 40 + lq * 8);
#pragma unroll
    for (int j = 0; j < 2; ++j)
      bF[j] = *(const bf16x8*)(Bs + (wc * 32 + j * 16 + lm) * 32 + lq * 8);
#pragma unroll
    for (int i = 0; i < 4; ++i)
#pragma unroll
      for (int j = 0; j < 2; ++j)
        acc[i][j] = __builtin_amdgcn_mfma_f32_16x16x32_bf16(aF[i], bF[j], acc[i][j], 0, 0, 0);
    __syncthreads();
  }

  int o0 = wc * 32;
  float sc[2], sh[2];
#pragma unroll
  for (int j = 0; j < 2; ++j) {
    int o = o0 + j * 16 + lm;
    sc[j] = scale1[o]; sh[j] = shift1[o];
  }
#pragma unroll
  for (int i = 0; i < 4; ++i) {
#pragma unroll
    for (int r = 0; r < 4; ++r) {
      int m = m0 + wr * 64 + i * 16 + lq * 4 + r;
      int b = m / 1444, q = m - b * 1444;
      int yy = q / 38, xx = q - yy * 38;
      size_t base = (((size_t)b * 21 + 1 + (yy >> 1)) * 21 + 1 + (xx >> 1)) * 1280
                  + ((yy & 1) * 2 + (xx & 1)) * 64;
#pragma unroll
      for (int j = 0; j < 2; ++j) {
        float v = acc[i][j][r] * sc[j] + sh[j];
        v = v > 0.f ? v : 0.1f * v;
        cat[base + o0 + j * 16 + lm] = f2bf(v);
      }
    }
  }
}

// ---------------- conv2 (3x3, 1280->1024) + BN + leaky -> pre[m][1024] bf16 ----------------
// Implicit GEMM, BK=64 (two 32-K panels). XCD-affinity swizzle: n0 = bid&7 so each
// XCD keeps ONE 2.95 MB B-slice L2-resident; all XCDs walk m0 together (A LLC-hot).
__global__ __launch_bounds__(256) void k_conv2(const u16* cat, const u16* w2t,
    const float* scale2, const float* shift2, u16* pre)
{
  __shared__ u16 As[8192];
  __shared__ u16 Bs[8192];
  int tid = threadIdx.x;
  int wave = tid >> 6, lane = tid & 63;
  int wr = wave >> 1, wc = wave & 1;
  int lm = lane & 15, lq = lane >> 4;
  int n0 = (blockIdx.x & 7) * 128;
  int m0 = (blockIdx.x >> 3) * 128;

  int rIn = lane >> 2;
  int kseg = (lane & 3) * 8;
  int rowLo = wave * 16 + rIn;

  int mLo = m0 + rowLo;       if (mLo > 23103) mLo = 23103;
  int mHi = m0 + rowLo + 64;  if (mHi > 23103) mHi = 23103;
  int bL = mLo / 361, pL = mLo - bL * 361, yL = pL / 19, xL = pL - yL * 19;
  int bH = mHi / 361, pH = mHi - bH * 361, yH = pH / 19, xH = pH - yH * 19;
  const u16* aLo = cat + ((size_t)(bL * 21 + yL) * 21 + xL) * 1280 + kseg;
  const u16* aHi = cat + ((size_t)(bH * 21 + yH) * 21 + xH) * 1280 + kseg;
  const u16* bLo = w2t + (size_t)(n0 + rowLo) * 3840 + kseg;
  const u16* bHi = bLo + (size_t)64 * 3840;

  u16* asJ0 = As + wave * 512;          u16* asJ1 = As + (4 + wave) * 512;
  u16* asJ2 = As + 4096 + wave * 512;   u16* asJ3 = As + 4096 + (4 + wave) * 512;
  u16* bsJ0 = Bs + wave * 512;          u16* bsJ1 = Bs + (4 + wave) * 512;
  u16* bsJ2 = Bs + 4096 + wave * 512;   u16* bsJ3 = Bs + 4096 + (4 + wave) * 512;

  f32x4 acc[4][4];
#pragma unroll
  for (int i = 0; i < 4; ++i)
#pragma unroll
    for (int j = 0; j < 4; ++j)
#pragma unroll
      for (int r = 0; r < 4; ++r) acc[i][j][r] = 0.f;

  for (int dy = 0; dy < 3; ++dy) {
    const u16* a0 = aLo + dy * 26880;
    const u16* a1 = aHi + dy * 26880;
    const u16* b0 = bLo + (size_t)dy * 3932160;
    const u16* b1 = bHi + (size_t)dy * 3932160;
    for (int k0 = 0; k0 < 3840; k0 += 64) {
      gld16(a0 + k0,      asJ0);
      gld16(a1 + k0,      asJ1);
      gld16(a0 + k0 + 32, asJ2);
      gld16(a1 + k0 + 32, asJ3);
      gld16(b0 + k0,      bsJ0);
      gld16(b1 + k0,      bsJ1);
      gld16(b0 + k0 + 32, bsJ2);
      gld16(b1 + k0 + 32, bsJ3);
      __syncthreads();
#pragma unroll
      for (int kk = 0; kk < 2; ++kk) {
        bf16x8 aF[4], bF[4];
#pragma unroll
        for (int i = 0; i < 4; ++i)
          aF[i] = *(const bf16x8*)(As + kk * 4096 + (wr * 64 + i * 16 + lm) * 32 + lq * 8);
#pragma unroll
        for (int j = 0; j < 4; ++j)
          bF[j] = *(const bf16x8*)(Bs + kk * 4096 + (wc * 64 + j * 16 + lm) * 32 + lq * 8);
#pragma unroll
        for (int i = 0; i < 4; ++i)
#pragma unroll
          for (int j = 0; j < 4; ++j)
            acc[i][j] = __builtin_amdgcn_mfma_f32_16x16x32_bf16(aF[i], bF[j], acc[i][j], 0, 0, 0);
      }
      __syncthreads();
    }
  }

  int nn[4]; float sc[4], sh[4];
#pragma unroll
  for (int j = 0; j < 4; ++j) {
    nn[j] = n0 + wc * 64 + j * 16 + lm;
    sc[j] = scale2[nn[j]]; sh[j] = shift2[nn[j]];
  }
#pragma unroll
  for (int i = 0; i < 4; ++i) {
#pragma unroll
    for (int r = 0; r < 4; ++r) {
      int m = m0 + wr * 64 + i * 16 + lq * 4 + r;
      if (m < 23104) {
        u16* row = pre + (size_t)m * 1024;
#pragma unroll
        for (int j = 0; j < 4; ++j) {
          float v = acc[i][j][r] * sc[j] + sh[j];
          v = v > 0.f ? v : 0.1f * v;
          row[nn[j]] = f2bf(v);
        }
      }
    }
  }
}

// ---------------- einsum: det[cw=600][pix=23104]; A=cwt(640x1024), B=pre(23104x1024) ----
// grid dim3(5,181): consecutive blocks share the same pre slice (LLC-hot).
__global__ __launch_bounds__(256) void k_einsum(const u16* pre, const u16* cwt,
    const float* cbf, float* out)
{
  __shared__ u16 As[4096];
  __shared__ u16 Bs[4096];
  int tid = threadIdx.x;
  int wave = tid >> 6, lane = tid & 63;
  int wr = wave >> 1, wc = wave & 1;
  int lm = lane & 15, lq = lane >> 4;
  int m0 = blockIdx.x * 128;   // cw-row block (0..512)
  int n0 = blockIdx.y * 128;   // pixel block

  int r0 = tid >> 2, seg = (tid & 3) * 8;
  const u16* aP0 = cwt + (size_t)(m0 + r0) * 1024 + seg;
  const u16* aP1 = aP0 + (size_t)64 * 1024;
  int q0 = n0 + r0;       if (q0 > 23103) q0 = 23103;
  int q1 = n0 + r0 + 64;  if (q1 > 23103) q1 = 23103;
  const u16* bP0 = pre + (size_t)q0 * 1024 + seg;
  const u16* bP1 = pre + (size_t)q1 * 1024 + seg;

  char* AsW = (char*)As + wave * 1024;
  char* BsW = (char*)Bs + wave * 1024;

  f32x4 acc[4][4];
#pragma unroll
  for (int i = 0; i < 4; ++i)
#pragma unroll
    for (int j = 0; j < 4; ++j)
#pragma unroll
      for (int r = 0; r < 4; ++r) acc[i][j][r] = 0.f;

  for (int k0 = 0; k0 < 1024; k0 += 32) {
    gld16(aP0 + k0, AsW);
    gld16(aP1 + k0, AsW + 4096);
    gld16(bP0 + k0, BsW);
    gld16(bP1 + k0, BsW + 4096);
    __syncthreads();
    bf16x8 aF[4], bF[4];
#pragma unroll
    for (int i = 0; i < 4; ++i)
      aF[i] = *(const bf16x8*)(As + (wr * 64 + i * 16 + lm) * 32 + lq * 8);
#pragma unroll
    for (int j = 0; j < 4; ++j)
      bF[j] = *(const bf16x8*)(Bs + (wc * 64 + j * 16 + lm) * 32 + lq * 8);
#pragma unroll
    for (int i = 0; i < 4; ++i)
#pragma unroll
      for (int j = 0; j < 4; ++j)
        acc[i][j] = __builtin_amdgcn_mfma_f32_16x16x32_bf16(aF[i], bF[j], acc[i][j], 0, 0, 0);
    __syncthreads();
  }

  int pix[4], pb[4], pp[4];
#pragma unroll
  for (int j = 0; j < 4; ++j) {
    pix[j] = n0 + wc * 64 + j * 16 + lm;
    int b = pix[j] / 361;
    pb[j] = b; pp[j] = pix[j] - b * 361;
  }
#pragma unroll
  for (int i = 0; i < 4; ++i) {
#pragma unroll
    for (int r = 0; r < 4; ++r) {
      int cw = m0 + wr * 64 + i * 16 + lq * 4 + r;
      if (cw < 600) {
        float bias = cbf[cw];
#pragma unroll
        for (int j = 0; j < 4; ++j) {
          if (pix[j] < 23104)
            out[(size_t)pb[j] * 216600 + (size_t)cw * 361 + pp[j]] = acc[i][j][r] + bias;
        }
      }
    }
  }
}

// ---------------- launch ----------------

extern "C" void kernel_launch(void* const* d_in, const int* in_sizes, int n_in,
                              void* d_out, int out_size, void* d_ws, size_t ws_size,
                              hipStream_t stream) {
  const float* feat0 = (const float*)d_in[0];
  const float* feat1 = (const float*)d_in[1];
  const float* w1 = (const float*)d_in[2];
  const float* g1 = (const float*)d_in[3];
  const float* b1 = (const float*)d_in[4];
  const float* m1 = (const float*)d_in[5];
  const float* v1 = (const float*)d_in[6];
  const float* w2 = (const float*)d_in[7];
  const float* g2 = (const float*)d_in[8];
  const float* b2 = (const float*)d_in[9];
  const float* m2 = (const float*)d_in[10];
  const float* v2 = (const float*)d_in[11];
  const float* rw = (const float*)d_in[12];
  float* out = (float*)d_out;

  char* ws = (char*)d_ws;
  u16* cat    = (u16*)(ws);                    // 72,253,440 B
  u16* w2t    = (u16*)(ws + 72253440);         // 23,592,960 B
  u16* pre    = (u16*)(ws + 95846400);         // 47,316,992 B
  u16* w1b    = (u16*)(ws + 143163392);
  u16* cwt    = (u16*)(ws + 143228928);
  float* scale1 = (float*)(ws + 144539648);
  float* shift1 = (float*)(ws + 144539904);
  float* scale2 = (float*)(ws + 144540160);
  float* shift2 = (float*)(ws + 144544256);
  float* cbf    = (float*)(ws + 144548352);

  hipMemsetAsync(cat, 0, 72253440, stream);  // zero spatial padding

  k_prep_small<<<2696, 256, 0, stream>>>(w1, rw, g1, b1, m1, v1, g2, b2, m2, v2,
                                         w1b, cwt, scale1, shift1, scale2, shift2, cbf);
  k_prep_w2<<<1024, 256, 0, stream>>>(w2, w2t);
  k_feat0<<<dim3(12, 32, 64), 256, 0, stream>>>(feat0, cat);
  k_conv1<<<722, 256, 0, stream>>>(feat1, w1b, scale1, shift1, cat);
  k_conv2<<<1448, 256, 0, stream>>>(cat, w2t, scale2, shift2, pre);
  k_einsum<<<dim3(5, 181), 256, 0, stream>>>(pre, cwt, cbf, out);
}